// Round 2
// baseline (24731.392 us; speedup 1.0000x reference)
//
#include <hip/hip_runtime.h>
#include <cstddef>
#include <cstdint>

// ---------------- problem constants ----------------
#define GROUPS 8     // batch groups; group g = blocks with blockIdx%8==g
#define WPG    32    // workgroups per group (each owns 16 j-columns)
#define BG     16    // batches per group  (8*16 = 128 = B)
#define JS     16    // hidden-j slice per WG
#define TPB    256
#define NT     1024  // timesteps
#define HDIM   512
#define INDIM  17
#define OUTDIM 17
#define BTOT   128
#define RING_D 4     // y0 ring depth (timesteps); max WG drift is 1, 4 is ample

typedef __attribute__((ext_vector_type(8))) short s8v;   // 8 x bf16 (MFMA A/B frag)
typedef __attribute__((ext_vector_type(4))) float f4v;   // MFMA C/D frag

// ---------------- workspace layout ----------------
// flags: 256 WGs x 64B slots                                   16 KB
// hbuf : [layer2][parity2][gr8][plane2][b16][j512] ushort       1 MB
// ring : [slot4][gr8][plane2][b16][k512] ushort                 2 MB
#define FLAGS_BYTES ((size_t)(256 * 16 * 4))
#define HBUF_OFF    FLAGS_BYTES
#define HBUF_ELEMS  ((size_t)2 * 2 * GROUPS * 2 * BG * HDIM)
#define RING_OFF    (HBUF_OFF + HBUF_ELEMS * 2)
#define RING_ELEMS  ((size_t)RING_D * GROUPS * 2 * BG * HDIM)
#define WS_NEEDED   (RING_OFF + RING_ELEMS * 2)   // ~3.2 MB

#define HIDX(ly, pp, gr, pl, b, j) \
  ((((((size_t)(ly) * 2 + (pp)) * GROUPS + (gr)) * 2 + (pl)) * BG + (b)) * HDIM + (j))
#define RIDX(sl, gr, pl, b, k) \
  (((((size_t)(sl) * GROUPS + (gr)) * 2 + (pl)) * BG + (b)) * HDIM + (k))

// ---------------- helpers ----------------
__device__ __forceinline__ unsigned short f2bf(float f) {
  unsigned int u = __float_as_uint(f);
  u += 0x7FFFu + ((u >> 16) & 1u);            // round-to-nearest-even
  return (unsigned short)(u >> 16);
}
__device__ __forceinline__ float bf2f(unsigned short h) {
  return __uint_as_float(((unsigned int)h) << 16);
}
__device__ __forceinline__ float sigm(float x) { return 1.f / (1.f + __expf(-x)); }
// inf-safe at both tails in fp32 (no NaN)
__device__ __forceinline__ float tanh_f(float x) { return 2.f / (1.f + __expf(-2.f * x)) - 1.f; }

#define MFMA(a, b, c) __builtin_amdgcn_mfma_f32_16x16x32_bf16((a), (b), (c), 0, 0, 0)

// ---------------- fused 2-layer persistent LSTM ----------------
// 256 WGs, 1/CU (VGPR-forced). Group gr = bid&7 owns batches [gr*16, gr*16+16).
// WG wg = bid>>3 owns j in [wg*16, wg*16+16) for BOTH layers. Wave = gate type.
// Super-step s (1..NT+1): L0 step s  and  L1 step s-1 (lag 1, y0 via ring).
// Weights stationary in VGPRs as MFMA B-frags, bf16 hi+lo split (wih1 hi-only).
__global__ __launch_bounds__(TPB, 1) void lstm_fused(
    const float* __restrict__ x,
    const float* __restrict__ wih0, const float* __restrict__ whh0,
    const float* __restrict__ bih0, const float* __restrict__ bhh0,
    const float* __restrict__ wih1, const float* __restrict__ whh1,
    const float* __restrict__ bih1, const float* __restrict__ bhh1,
    unsigned short* __restrict__ hbuf,
    unsigned short* __restrict__ ring,
    int* __restrict__ flags)
{
  const int bid  = blockIdx.x;
  const int gr   = bid & 7;
  const int wg   = bid >> 3;
  const int j0   = wg * JS;
  const int tid  = threadIdx.x;
  const int wave = tid >> 6;
  const int lane = tid & 63;
  const int n    = lane & 15;        // frag col (j within slice / batch for A)
  const int k0   = (lane >> 4) * 8;  // frag k base

  __shared__ float lds_g[4 * 256];   // gate preacts [gate][b*16+j]
  __shared__ float xs[16 * 32];      // L0 x_t staging, zero-padded K=32

  // ---- stationary weight B-fragments ----
  const int row = wave * HDIM + j0 + n;   // gate row in [0,2048): i,f,g,o blocks
  s8v w0x_h, w0x_l;                       // wih0: K=17 -> single padded k-tile
  {
    const float* wr = wih0 + (size_t)row * INDIM;
#pragma unroll
    for (int j = 0; j < 8; ++j) {
      int k = k0 + j;
      float v = (k < INDIM) ? wr[k] : 0.f;
      unsigned short hi = f2bf(v);
      w0x_h[j] = (short)hi;
      w0x_l[j] = (short)f2bf(v - bf2f(hi));
    }
  }
  s8v w0h_h[16], w0h_l[16];
  {
    const float* wr = whh0 + (size_t)row * HDIM;
#pragma unroll
    for (int kt = 0; kt < 16; ++kt)
#pragma unroll
      for (int j = 0; j < 8; ++j) {
        float v = wr[kt * 32 + k0 + j];
        unsigned short hi = f2bf(v);
        w0h_h[kt][j] = (short)hi;
        w0h_l[kt][j] = (short)f2bf(v - bf2f(hi));
      }
  }
  s8v w1x_h[16];                          // wih1: hi-only (register budget; ~1e-3 output err)
  {
    const float* wr = wih1 + (size_t)row * HDIM;
#pragma unroll
    for (int kt = 0; kt < 16; ++kt)
#pragma unroll
      for (int j = 0; j < 8; ++j)
        w1x_h[kt][j] = (short)f2bf(wr[kt * 32 + k0 + j]);
  }
  s8v w1h_h[16], w1h_l[16];
  {
    const float* wr = whh1 + (size_t)row * HDIM;
#pragma unroll
    for (int kt = 0; kt < 16; ++kt)
#pragma unroll
      for (int j = 0; j < 8; ++j) {
        float v = wr[kt * 32 + k0 + j];
        unsigned short hi = f2bf(v);
        w1h_h[kt][j] = (short)hi;
        w1h_l[kt][j] = (short)f2bf(v - bf2f(hi));
      }
  }
  const float b0 = bih0[row] + bhh0[row];
  const float b1 = bih1[row] + bhh1[row];

  float c0 = 0.f, c1 = 0.f;  // cell state for (b_l = tid>>4, j_l = tid&15)

  // ---- init h0[0] = h1[0] = 0 (parity 0), publish flag = 1 ----
  {
    int b_l = tid >> 4, j_l = tid & 15, jg = j0 + j_l;
    hbuf[HIDX(0, 0, gr, 0, b_l, jg)] = 0;
    hbuf[HIDX(0, 0, gr, 1, b_l, jg)] = 0;
    hbuf[HIDX(1, 0, gr, 0, b_l, jg)] = 0;
    hbuf[HIDX(1, 0, gr, 1, b_l, jg)] = 0;
  }
  __syncthreads();
  if (tid == 0)
    __hip_atomic_store(&flags[bid * 16], 1, __ATOMIC_RELEASE, __HIP_MEMORY_SCOPE_AGENT);

  // ---- super-steps ----
  for (int s = 1; s <= NT + 1; ++s) {
    const bool doL0 = (s <= NT);
    f4v acc0 = {b0, b0, b0, b0};

    // L0 x-part: no dependency on peers -> do before the flag wait
    if (doL0) {
      const int t = s - 1;
      for (int i = tid; i < 512; i += TPB) {
        int br = i >> 5, col = i & 31;
        xs[i] = (col < INDIM) ? x[((size_t)(gr * BG + br) * NT + t) * INDIM + col] : 0.f;
      }
      __syncthreads();
      s8v axh, axl;
#pragma unroll
      for (int j = 0; j < 8; ++j) {
        float v = xs[n * 32 + k0 + j];
        unsigned short hi = f2bf(v);
        axh[j] = (short)hi;
        axl[j] = (short)f2bf(v - bf2f(hi));
      }
      acc0 = MFMA(axh, w0x_h, acc0);
      acc0 = MFMA(axl, w0x_h, acc0);
      acc0 = MFMA(axh, w0x_l, acc0);
    }

    // wait: all 32 group peers completed super-step s-1
    if (tid < WPG) {
      const int* fp = &flags[(tid * 8 + gr) * 16];
      while (__hip_atomic_load(fp, __ATOMIC_RELAXED, __HIP_MEMORY_SCOPE_AGENT) < s)
        __builtin_amdgcn_s_sleep(1);
    }
    __syncthreads();
    __builtin_amdgcn_fence(__ATOMIC_ACQUIRE, "agent");

    // ---- L0: h-part + gate update -> h0[s], ring y0[s-1] ----
    if (doL0) {
      const int pp = (s - 1) & 1;
      const unsigned short* ph = hbuf + HIDX(0, pp, gr, 0, n, k0);
      const unsigned short* pl = hbuf + HIDX(0, pp, gr, 1, n, k0);
      f4v chh = {0.f, 0.f, 0.f, 0.f}, clh = {0.f, 0.f, 0.f, 0.f}, chl = {0.f, 0.f, 0.f, 0.f};
#pragma unroll
      for (int kt = 0; kt < 16; ++kt) {   // 3 independent acc chains: hide MFMA latency
        s8v ah = *(const s8v*)(ph + kt * 32);
        s8v al = *(const s8v*)(pl + kt * 32);
        chh = MFMA(ah, w0h_h[kt], chh);
        clh = MFMA(al, w0h_h[kt], clh);
        chl = MFMA(ah, w0h_l[kt], chl);
      }
      f4v g = acc0 + chh + clh + chl;
#pragma unroll
      for (int r = 0; r < 4; ++r)         // D frag: col=lane&15, row=(lane>>4)*4+r
        lds_g[wave * 256 + ((lane >> 4) * 4 + r) * 16 + n] = g[r];
      __syncthreads();
      {
        int j_l = tid & 15, b_l = tid >> 4, jg = j0 + j_l;
        float pi = lds_g[0 * 256 + b_l * 16 + j_l];
        float pf = lds_g[1 * 256 + b_l * 16 + j_l];
        float pg = lds_g[2 * 256 + b_l * 16 + j_l];
        float po = lds_g[3 * 256 + b_l * 16 + j_l];
        float ig = sigm(pi), fg = sigm(pf), og = sigm(po), gg = tanh_f(pg);
        c0 = fg * c0 + ig * gg;
        float h = og * tanh_f(c0);
        unsigned short hh = f2bf(h);
        unsigned short hl = f2bf(h - bf2f(hh));
        int pw = s & 1, sl = (s - 1) & (RING_D - 1);
        hbuf[HIDX(0, pw, gr, 0, b_l, jg)] = hh;
        hbuf[HIDX(0, pw, gr, 1, b_l, jg)] = hl;
        ring[RIDX(sl, gr, 0, b_l, jg)] = hh;   // y0 timestep s-1
        ring[RIDX(sl, gr, 1, b_l, jg)] = hl;
      }
      __syncthreads();   // lds_g consumed; safe for L1 to overwrite
    }

    // ---- L1: step s1 = s-1 consumes ring y0[s-2] (written super-step s-1) ----
    if (s >= 2) {
      const int s1 = s - 1, t1 = s - 2;
      const int sl = t1 & (RING_D - 1);
      const unsigned short* rh = ring + RIDX(sl, gr, 0, n, k0);
      const unsigned short* rl = ring + RIDX(sl, gr, 1, n, k0);
      f4v xh = {0.f, 0.f, 0.f, 0.f}, xl = {0.f, 0.f, 0.f, 0.f};
#pragma unroll
      for (int kt = 0; kt < 16; ++kt) {
        s8v ah = *(const s8v*)(rh + kt * 32);
        s8v al = *(const s8v*)(rl + kt * 32);
        xh = MFMA(ah, w1x_h[kt], xh);
        xl = MFMA(al, w1x_h[kt], xl);
      }
      const int pp1 = (s1 - 1) & 1;
      const unsigned short* qh = hbuf + HIDX(1, pp1, gr, 0, n, k0);
      const unsigned short* ql = hbuf + HIDX(1, pp1, gr, 1, n, k0);
      f4v chh = {0.f, 0.f, 0.f, 0.f}, clh = {0.f, 0.f, 0.f, 0.f}, chl = {0.f, 0.f, 0.f, 0.f};
#pragma unroll
      for (int kt = 0; kt < 16; ++kt) {
        s8v ah = *(const s8v*)(qh + kt * 32);
        s8v al = *(const s8v*)(ql + kt * 32);
        chh = MFMA(ah, w1h_h[kt], chh);
        clh = MFMA(al, w1h_h[kt], clh);
        chl = MFMA(ah, w1h_l[kt], chl);
      }
      f4v g = xh + xl + chh + clh + chl;
#pragma unroll
      for (int r = 0; r < 4; ++r)
        lds_g[wave * 256 + ((lane >> 4) * 4 + r) * 16 + n] = g[r] + b1;
      __syncthreads();
      {
        int j_l = tid & 15, b_l = tid >> 4, jg = j0 + j_l;
        float pi = lds_g[0 * 256 + b_l * 16 + j_l];
        float pf = lds_g[1 * 256 + b_l * 16 + j_l];
        float pg = lds_g[2 * 256 + b_l * 16 + j_l];
        float po = lds_g[3 * 256 + b_l * 16 + j_l];
        float ig = sigm(pi), fg = sigm(pf), og = sigm(po), gg = tanh_f(pg);
        c1 = fg * c1 + ig * gg;
        float h = og * tanh_f(c1);
        unsigned short hh = f2bf(h);
        unsigned short hl = f2bf(h - bf2f(hh));
        int pw = s1 & 1;
        hbuf[HIDX(1, pw, gr, 0, b_l, jg)] = hh;
        hbuf[HIDX(1, pw, gr, 1, b_l, jg)] = hl;
      }
      __syncthreads();   // drain stores before publish
    }

    if (doL0 && tid == 0)   // publish super-step s complete (release: peers on any XCD)
      __hip_atomic_store(&flags[bid * 16], s + 1, __ATOMIC_RELEASE, __HIP_MEMORY_SCOPE_AGENT);
  }
}

// ---------------- final linear: out = h1[NT] @ lin_w^T + lin_b ----------------
__global__ void final_linear(const unsigned short* __restrict__ hbuf,
                             const float* __restrict__ lin_w,
                             const float* __restrict__ lin_b,
                             float* __restrict__ out) {
  int b = blockIdx.x;      // 0..127
  int o = threadIdx.x;     // 64 threads, 17 active
  int gr = b >> 4, b_l = b & 15;
  if (o < OUTDIM) {
    float acc = lin_b[o];
    const unsigned short* ph = hbuf + HIDX(1, 0, gr, 0, b_l, 0);  // h1[1024]: parity 0
    const unsigned short* pl = hbuf + HIDX(1, 0, gr, 1, b_l, 0);
    for (int j = 0; j < HDIM; ++j) {
      float h = bf2f(ph[j]) + bf2f(pl[j]);
      acc += h * lin_w[(size_t)o * HDIM + j];
    }
    out[b * OUTDIM + o] = acc;
  }
}

__global__ void init_flags(int* __restrict__ flags) {
  int i = blockIdx.x * TPB + threadIdx.x;
  if (i < 256 * 16) flags[i] = 0;
}

__global__ void sentinel_kernel(float* __restrict__ out, int nv) {
  int i = blockIdx.x * TPB + threadIdx.x;
  if (i < nv) out[i] = 1e30f;  // unambiguous "workspace too small" marker
}

// ---------------- launch ----------------
extern "C" void kernel_launch(void* const* d_in, const int* in_sizes, int n_in,
                              void* d_out, int out_size, void* d_ws, size_t ws_size,
                              hipStream_t stream) {
  const float* x     = (const float*)d_in[0];
  const float* wih0  = (const float*)d_in[1];
  const float* whh0  = (const float*)d_in[2];
  const float* bih0  = (const float*)d_in[3];
  const float* bhh0  = (const float*)d_in[4];
  const float* wih1  = (const float*)d_in[5];
  const float* whh1  = (const float*)d_in[6];
  const float* bih1  = (const float*)d_in[7];
  const float* bhh1  = (const float*)d_in[8];
  const float* lin_w = (const float*)d_in[9];
  const float* lin_b = (const float*)d_in[10];
  float* out = (float*)d_out;
  char* ws = (char*)d_ws;

  if (ws_size < WS_NEEDED) {
    sentinel_kernel<<<(out_size + TPB - 1) / TPB, TPB, 0, stream>>>(out, out_size);
    return;
  }

  int* flags = (int*)ws;
  unsigned short* hbuf = (unsigned short*)(ws + HBUF_OFF);
  unsigned short* ring = (unsigned short*)(ws + RING_OFF);

  init_flags<<<(256 * 16 + TPB - 1) / TPB, TPB, 0, stream>>>(flags);
  lstm_fused<<<256, TPB, 0, stream>>>(x, wih0, whh0, bih0, bhh0,
                                      wih1, whh1, bih1, bhh1, hbuf, ring, flags);
  final_linear<<<BTOT, 64, 0, stream>>>(hbuf, lin_w, lin_b, out);
}

// Round 3
// 5471.968 us; speedup vs baseline: 4.5197x; 4.5197x over previous
//
#include <hip/hip_runtime.h>
#include <cstddef>
#include <cstdint>

typedef unsigned long long ull;
typedef unsigned short u16;
typedef __attribute__((ext_vector_type(8))) short s8v;   // 8 x bf16 (MFMA A/B frag)
typedef __attribute__((ext_vector_type(4))) float f4v;   // MFMA C/D frag

#define GROUPS 8
#define WPG    32
#define BG     16
#define JS     16
#define TPB    256
#define NT     1024
#define HDIM   512
#define INDIM  17
#define OUTDIM 17
#define BTOT   128
#define RING_D 4

// All cross-WG traffic uses relaxed agent-scope atomics (sc1: bypass L1/L2,
// serviced at MALL). NO fences anywhere -> no per-step buffer_wbl2/inv.
#define AT_LD(p)   __hip_atomic_load((p), __ATOMIC_RELAXED, __HIP_MEMORY_SCOPE_AGENT)
#define AT_ST(p,v) __hip_atomic_store((p), (v), __ATOMIC_RELAXED, __HIP_MEMORY_SCOPE_AGENT)

// ---------------- workspace ----------------
#define FLAGS_INTS (256 * 16)                       // 64B-stride flag slots
#define RING_OFF   ((size_t)FLAGS_INTS * 4)
#define RING_ELEMS ((size_t)RING_D * GROUPS * 2 * BG * HDIM)   // h0 ring (hi/lo planes)
#define H1_OFF     (RING_OFF + RING_ELEMS * 2)
#define H1_ELEMS   ((size_t)2 * GROUPS * 2 * BG * HDIM)        // h1 double buffer
#define WS_NEEDED  (H1_OFF + H1_ELEMS * 2)          // ~1.6 MB

#define RIDX(sl, gr, pl, b, j) \
  (((((size_t)(sl) * GROUPS + (gr)) * 2 + (pl)) * BG + (b)) * HDIM + (j))
#define H1IDX(pp, gr, pl, b, j) \
  (((((size_t)(pp) * GROUPS + (gr)) * 2 + (pl)) * BG + (b)) * HDIM + (j))

// ---------------- helpers ----------------
__device__ __forceinline__ u16 f2bf(float f) {
  unsigned int u = __float_as_uint(f);
  u += 0x7FFFu + ((u >> 16) & 1u);
  return (u16)(u >> 16);
}
__device__ __forceinline__ float bf2f(u16 h) {
  return __uint_as_float(((unsigned int)h) << 16);
}
__device__ __forceinline__ float sigm(float x) { return 1.f / (1.f + __expf(-x)); }
__device__ __forceinline__ float tanh_f(float x) { return 2.f / (1.f + __expf(-2.f * x)) - 1.f; }

#define MFMA(a, b, c) __builtin_amdgcn_mfma_f32_16x16x32_bf16((a), (b), (c), 0, 0, 0)

// ---------------- fused 2-layer persistent LSTM ----------------
// 256 WGs (1/CU). Group gr = bid&7 owns batches [gr*16, gr*16+16).
// WG wg = bid>>3 owns j-slice [wg*16, wg*16+16) for both layers; wave = gate.
// Super-step s: L0 step s, L1 step s-1.  Invariant: L0's recurrent input
// h0[s-1] IS L1's x-input y0[s-2] -> one staged tile feeds both chains.
__global__ __launch_bounds__(TPB, 1) void lstm_fused(
    const float* __restrict__ x,
    const float* __restrict__ wih0, const float* __restrict__ whh0,
    const float* __restrict__ bih0, const float* __restrict__ bhh0,
    const float* __restrict__ wih1, const float* __restrict__ whh1,
    const float* __restrict__ bih1, const float* __restrict__ bhh1,
    u16* __restrict__ ring,   // h0 ring [slot4][gr][pl2][b16][j512]
    u16* __restrict__ h1b,    // h1 dbuf [pp2][gr][pl2][b16][j512]
    int* __restrict__ flags)
{
  const int bid  = blockIdx.x;
  const int gr   = bid & 7;
  const int wg   = bid >> 3;
  const int j0   = wg * JS;
  const int tid  = threadIdx.x;
  const int wave = tid >> 6;
  const int lane = tid & 63;
  const int n    = lane & 15;        // A-frag row (batch) / B-frag col (j)
  const int q    = lane >> 4;        // k-quad
  const int k0   = q * 8;

  // 64 KB LDS: buf0 = h0 tile (2 planes x 16KB), buf1 = h1 tile.
  // Gate-exchange scratch (8 KB) aliases buf0 (consumed before reuse).
  __shared__ char smem[65536];
  char* b0h = smem;                 // h0 hi plane
  char* b0l = smem + 16384;         // h0 lo plane
  char* b1h = smem + 32768;         // h1 hi plane
  char* b1l = smem + 49152;         // h1 lo plane
  float* ldsg = (float*)smem;       // [8 gates][256] aliases buf0

  // ---- stationary weight B-fragments (bf16 hi+lo; wih1 hi-only) ----
  const int row = wave * HDIM + j0 + n;
  s8v w0x_h, w0x_l;
  {
    const float* wr = wih0 + (size_t)row * INDIM;
#pragma unroll
    for (int j = 0; j < 8; ++j) {
      int k = k0 + j;
      float v = (k < INDIM) ? wr[k] : 0.f;
      u16 hi = f2bf(v);
      w0x_h[j] = (short)hi;
      w0x_l[j] = (short)f2bf(v - bf2f(hi));
    }
  }
  s8v w0h_h[16], w0h_l[16];
  {
    const float* wr = whh0 + (size_t)row * HDIM;
#pragma unroll
    for (int kt = 0; kt < 16; ++kt)
#pragma unroll
      for (int j = 0; j < 8; ++j) {
        float v = wr[kt * 32 + k0 + j];
        u16 hi = f2bf(v);
        w0h_h[kt][j] = (short)hi;
        w0h_l[kt][j] = (short)f2bf(v - bf2f(hi));
      }
  }
  s8v w1x_h[16];
  {
    const float* wr = wih1 + (size_t)row * HDIM;
#pragma unroll
    for (int kt = 0; kt < 16; ++kt)
#pragma unroll
      for (int j = 0; j < 8; ++j)
        w1x_h[kt][j] = (short)f2bf(wr[kt * 32 + k0 + j]);
  }
  s8v w1h_h[16], w1h_l[16];
  {
    const float* wr = whh1 + (size_t)row * HDIM;
#pragma unroll
    for (int kt = 0; kt < 16; ++kt)
#pragma unroll
      for (int j = 0; j < 8; ++j) {
        float v = wr[kt * 32 + k0 + j];
        u16 hi = f2bf(v);
        w1h_h[kt][j] = (short)hi;
        w1h_l[kt][j] = (short)f2bf(v - bf2f(hi));
      }
  }
  const float b0v = bih0[row] + bhh0[row];
  const float b1v = bih1[row] + bhh1[row];

  float c0 = 0.f, c1 = 0.f;
  const int b_l = tid >> 4, j_l = tid & 15, jg = j0 + j_l;

  // ---- init h0 ring slot0 = 0, h1 parity0 = 0 (atomic -> visible at MALL) ----
  AT_ST(&ring[RIDX(0, gr, 0, b_l, jg)], (u16)0);
  AT_ST(&ring[RIDX(0, gr, 1, b_l, jg)], (u16)0);
  AT_ST(&h1b[H1IDX(0, gr, 0, b_l, jg)], (u16)0);
  AT_ST(&h1b[H1IDX(0, gr, 1, b_l, jg)], (u16)0);
  __syncthreads();  // implicit vmcnt(0): stores visible before flag
  if (tid == 0) AT_ST(&flags[bid * 16], 1);

  for (int s = 1; s <= NT + 1; ++s) {
    const bool doL0 = (s <= NT);
    const bool doL1 = (s >= 2);

    // L0 x-part (no peer dependency): issue before the wait
    f4v a0 = {b0v, b0v, b0v, b0v};
    if (doL0) {
      const int t = s - 1;
      const float* xr = x + ((size_t)(gr * BG + n) * NT + t) * INDIM;
      s8v axh, axl;
#pragma unroll
      for (int j = 0; j < 8; ++j) {
        int k = k0 + j;
        float v = (k < INDIM) ? xr[k] : 0.f;
        u16 hi = f2bf(v);
        axh[j] = (short)hi;
        axl[j] = (short)f2bf(v - bf2f(hi));
      }
      a0 = MFMA(axh, w0x_h, a0);
      a0 = MFMA(axl, w0x_h, a0);
      a0 = MFMA(axh, w0x_l, a0);
    }

    // wait for all 32 group peers to have published step s-1
    if (tid < WPG) {
      const int* fp = &flags[(tid * 8 + gr) * 16];
      while (AT_LD(fp) < s) __builtin_amdgcn_s_sleep(1);
    }
    __syncthreads();

    // ---- stage h0[s-1] (= y0[s-2]) and h1[s-2] tiles: MALL -> LDS ----
    {
      const int sl  = (s - 1) & (RING_D - 1);
      const int pp1 = s & 1;  // h1[s-2] parity
      const ull* g0h = (const ull*)(ring + RIDX(sl, gr, 0, 0, 0));
      const ull* g0l = (const ull*)(ring + RIDX(sl, gr, 1, 0, 0));
      const ull* g1h = (const ull*)(h1b + H1IDX(pp1, gr, 0, 0, 0));
      const ull* g1l = (const ull*)(h1b + H1IDX(pp1, gr, 1, 0, 0));
      ull v0h[8], v0l[8], v1h[8], v1l[8];
#pragma unroll
      for (int r = 0; r < 8; ++r) {
        int c = r * 256 + tid;          // 8B chunk: b = c>>7, k4 = c&127
        v0h[r] = AT_LD(g0h + c);
        v0l[r] = AT_LD(g0l + c);
        v1h[r] = AT_LD(g1h + c);
        v1l[r] = AT_LD(g1l + c);
      }
#pragma unroll
      for (int r = 0; r < 8; ++r) {
        int c = r * 256 + tid;
        int b = c >> 7, k4 = c & 127;
        int off = b * 1024 + ((k4 * 8) ^ ((b & 7) * 16));  // swizzled
        *(ull*)(b0h + off) = v0h[r];
        *(ull*)(b0l + off) = v0l[r];
        *(ull*)(b1h + off) = v1h[r];
        *(ull*)(b1l + off) = v1l[r];
      }
    }
    __syncthreads();

    // ---- K-loop A: shared h0 tile -> L0-h (3 chains) + L1-x (2 chains) ----
    f4v z = {0.f, 0.f, 0.f, 0.f};
    f4v cA1 = z, cA2 = z, cB0 = {b1v, b1v, b1v, b1v}, cB1 = z;
#pragma unroll
    for (int kt = 0; kt < 16; ++kt) {
      int off = n * 1024 + ((kt * 64 + q * 16) ^ ((n & 7) * 16));
      s8v ah = *(const s8v*)(b0h + off);
      s8v al = *(const s8v*)(b0l + off);
      a0  = MFMA(ah, w0h_h[kt], a0);
      cA1 = MFMA(al, w0h_h[kt], cA1);
      cA2 = MFMA(ah, w0h_l[kt], cA2);
      cB0 = MFMA(ah, w1x_h[kt], cB0);
      cB1 = MFMA(al, w1x_h[kt], cB1);
    }
    // ---- K-loop B: h1 tile -> L1-h (3 chains) ----
    f4v cC0 = z, cC1 = z, cC2 = z;
#pragma unroll
    for (int kt = 0; kt < 16; ++kt) {
      int off = n * 1024 + ((kt * 64 + q * 16) ^ ((n & 7) * 16));
      s8v ah = *(const s8v*)(b1h + off);
      s8v al = *(const s8v*)(b1l + off);
      cC0 = MFMA(ah, w1h_h[kt], cC0);
      cC1 = MFMA(al, w1h_h[kt], cC1);
      cC2 = MFMA(ah, w1h_l[kt], cC2);
    }
    __syncthreads();  // buf0 ds_reads complete; ldsg may alias it now

    // ---- gate exchange (both layers, one barrier pair) ----
    if (doL0) {
      f4v g = a0 + cA1 + cA2;
#pragma unroll
      for (int r = 0; r < 4; ++r) ldsg[wave * 256 + (q * 4 + r) * 16 + n] = g[r];
    }
    if (doL1) {
      f4v g = cB0 + cB1 + cC0 + cC1 + cC2;
#pragma unroll
      for (int r = 0; r < 4; ++r) ldsg[(4 + wave) * 256 + (q * 4 + r) * 16 + n] = g[r];
    }
    __syncthreads();

    // ---- elementwise updates: thread -> (b_l, j_l) ----
    if (doL0) {
      float pi = ldsg[0 * 256 + tid], pf = ldsg[1 * 256 + tid];
      float pg = ldsg[2 * 256 + tid], po = ldsg[3 * 256 + tid];
      float ig = sigm(pi), fg = sigm(pf), og = sigm(po), gg = tanh_f(pg);
      c0 = fg * c0 + ig * gg;
      float h = og * tanh_f(c0);
      u16 hh = f2bf(h), hl = f2bf(h - bf2f(hh));
      int sl = s & (RING_D - 1);
      AT_ST(&ring[RIDX(sl, gr, 0, b_l, jg)], hh);
      AT_ST(&ring[RIDX(sl, gr, 1, b_l, jg)], hl);
    }
    if (doL1) {
      float pi = ldsg[4 * 256 + tid], pf = ldsg[5 * 256 + tid];
      float pg = ldsg[6 * 256 + tid], po = ldsg[7 * 256 + tid];
      float ig = sigm(pi), fg = sigm(pf), og = sigm(po), gg = tanh_f(pg);
      c1 = fg * c1 + ig * gg;
      float h = og * tanh_f(c1);
      u16 hh = f2bf(h), hl = f2bf(h - bf2f(hh));
      int pw = (s - 1) & 1;
      AT_ST(&h1b[H1IDX(pw, gr, 0, b_l, jg)], hh);
      AT_ST(&h1b[H1IDX(pw, gr, 1, b_l, jg)], hl);
    }
    __syncthreads();  // implicit vmcnt(0): all waves' h stores at MALL
    if (doL0 && tid == 0) AT_ST(&flags[bid * 16], s + 1);
  }
}

// ---------------- final linear: out = h1[NT] @ lin_w^T + lin_b ----------------
__global__ void final_linear(const u16* __restrict__ h1b,
                             const float* __restrict__ lin_w,
                             const float* __restrict__ lin_b,
                             float* __restrict__ out) {
  int b = blockIdx.x, o = threadIdx.x;
  int gr = b >> 4, b_l = b & 15;
  if (o < OUTDIM) {
    float acc = lin_b[o];
    const u16* ph = h1b + H1IDX(0, gr, 0, b_l, 0);  // h1[1024]: parity 0
    const u16* pl = h1b + H1IDX(0, gr, 1, b_l, 0);
    for (int j = 0; j < HDIM; ++j) {
      float h = bf2f(ph[j]) + bf2f(pl[j]);
      acc += h * lin_w[(size_t)o * HDIM + j];
    }
    out[b * OUTDIM + o] = acc;
  }
}

__global__ void init_flags(int* __restrict__ flags) {
  int i = blockIdx.x * TPB + threadIdx.x;
  if (i < FLAGS_INTS) flags[i] = 0;
}

__global__ void sentinel_kernel(float* __restrict__ out, int nv) {
  int i = blockIdx.x * TPB + threadIdx.x;
  if (i < nv) out[i] = 1e30f;
}

extern "C" void kernel_launch(void* const* d_in, const int* in_sizes, int n_in,
                              void* d_out, int out_size, void* d_ws, size_t ws_size,
                              hipStream_t stream) {
  const float* x     = (const float*)d_in[0];
  const float* wih0  = (const float*)d_in[1];
  const float* whh0  = (const float*)d_in[2];
  const float* bih0  = (const float*)d_in[3];
  const float* bhh0  = (const float*)d_in[4];
  const float* wih1  = (const float*)d_in[5];
  const float* whh1  = (const float*)d_in[6];
  const float* bih1  = (const float*)d_in[7];
  const float* bhh1  = (const float*)d_in[8];
  const float* lin_w = (const float*)d_in[9];
  const float* lin_b = (const float*)d_in[10];
  float* out = (float*)d_out;
  char* ws = (char*)d_ws;

  if (ws_size < WS_NEEDED) {
    sentinel_kernel<<<(out_size + TPB - 1) / TPB, TPB, 0, stream>>>(out, out_size);
    return;
  }

  int* flags = (int*)ws;
  u16* ring  = (u16*)(ws + RING_OFF);
  u16* h1b   = (u16*)(ws + H1_OFF);

  init_flags<<<(FLAGS_INTS + TPB - 1) / TPB, TPB, 0, stream>>>(flags);
  lstm_fused<<<256, TPB, 0, stream>>>(x, wih0, whh0, bih0, bhh0,
                                      wih1, whh1, bih1, bhh1, ring, h1b, flags);
  final_linear<<<BTOT, 64, 0, stream>>>(h1b, lin_w, lin_b, out);
}